// Round 21
// baseline (294.998 us; speedup 1.0000x reference)
//
#include <hip/hip_runtime.h>
#include <hip/hip_bf16.h>

// Channel attention (4 heads, dilated 3x3 key convs d=1,2,4,8), f16 MFMA pipeline.
// R21: convk -- weight fragments now loaded global->register in-compute (L2-hot,
// frag-native Wkb), removing 18 of 36 ds_reads per 72 MFMAs (the LDS-BW bound);
// WSTAGE deleted, LDS 77.8->66.6KB. outk2 reverted to R19 direct form (R20's
// LDS staging measured neutral-negative). Everything else = R19/R20.
//
// ws layout (bytes):
//   A2   : [0, 1Mi)            f16 A2 = attn@Wv ; obias fp32 [1048576,1056768)
//   xT2  : [67108864,134217728) f16 [b][slab16][n][16]
//   attn : [134217728,134479872) f16 [h][b][o][p]
//   Wqvn : [134479872,134610944) f16 q A-frag-native [mt8][ks16][hi2][m32][8]
//   WvT  : [134610944,134742016) f16 [h][c256][p64]
//   Wkb  : [134742016,135921664) f16 [h][t][ks32][p64][8]
//   zpage: [135921664,135922176) zeros
// d_out scratch: part fp32 [0,16Mi); qf f16 [64Mi,128Mi)

typedef __attribute__((ext_vector_type(8))) _Float16 f16x8;
typedef __attribute__((ext_vector_type(4))) float f32x4;
typedef __attribute__((ext_vector_type(16))) float f32x16;

__device__ __forceinline__ unsigned short f2h(float f) {
  union { _Float16 h; unsigned short u; } v;
  v.h = (_Float16)f;
  return v.u;
}

__device__ __forceinline__ f32x16 mfma32(f16x8 a, f16x8 b, f32x16 c) {
  return __builtin_amdgcn_mfma_f32_32x32x16_f16(a, b, c, 0, 0, 0);
}

// ---------------- weight prep ----------------
__global__ __launch_bounds__(256) void prep(const float* __restrict__ Wq,
                                            const float* __restrict__ Wv,
                                            const float* __restrict__ Wk,
                                            unsigned short* __restrict__ Wqvn,
                                            unsigned short* __restrict__ Wkb,
                                            unsigned short* __restrict__ zp) {
  int i = blockIdx.x * 256 + threadIdx.x;
  if (blockIdx.x == 0) zp[threadIdx.x] = 0;  // 512 B zero page
  const int total = 131072 + 589824;
  if (i >= total) return;
  if (i < 65536) {
    int jj = i & 7;
    int m31 = (i >> 3) & 31;
    int hi = (i >> 8) & 1;
    int ks = (i >> 9) & 15;
    int mt = i >> 13;
    int row = mt * 32 + m31;
    int ch = ks * 16 + hi * 8 + jj;
    Wqvn[i] = f2h(Wq[row * 256 + ch]);
  } else if (i < 131072) {
    int j2 = i - 65536;
    int p = j2 & 63;
    int c = (j2 >> 6) & 255;
    int h = j2 >> 14;
    Wqvn[i] = f2h(Wv[(size_t)(h * 64 + p) * 256 + c]);
  } else {
    int j = i - 131072;  // (((h*9+t)*32 + ks)*64 + p)*8 + jj
    int jj = j & 7;
    int p = (j >> 3) & 63;
    int ks = (j >> 9) & 31;
    int ht = j >> 14;
    int t = ht % 9;
    int h = ht / 9;
    Wkb[j] = f2h(Wk[(size_t)((h * 64 + p) * 256 + ks * 8 + jj) * 9 + t]);
  }
}

// ---------------- fused xpose + q-projection (R19, unchanged) -----------------
__global__ __launch_bounds__(256) void xproj(const float* __restrict__ x,
                                             const unsigned short* __restrict__ Wqvn,
                                             const float* __restrict__ bq,
                                             unsigned short* __restrict__ xT,
                                             unsigned short* __restrict__ qf) {
  __shared__ unsigned short tile[64][66];
  __shared__ __align__(16) unsigned short Xs[2048 * 8];
  __shared__ __align__(16) unsigned short Ls[64 * 264];
  int n0 = blockIdx.x * 64, b = blockIdx.y;
  int tid = threadIdx.x, lane = tid & 63, w = tid >> 6;
  int l31 = lane & 31, hi = lane >> 5;

#pragma unroll 1
  for (int ct = 0; ct < 4; ct++) {
    int c0 = ct * 64;
    int r = tid >> 2, q = tid & 3;
    const float* src = x + (size_t)b * 4194304 + (size_t)(c0 + r) * 16384 + n0 + q * 16;
#pragma unroll
    for (int i = 0; i < 4; i++) {
      float4 v = *(const float4*)(src + i * 4);
      tile[r][q * 16 + i * 4 + 0] = f2h(v.x);
      tile[r][q * 16 + i * 4 + 1] = f2h(v.y);
      tile[r][q * 16 + i * 4 + 2] = f2h(v.z);
      tile[r][q * 16 + i * 4 + 3] = f2h(v.w);
    }
    __syncthreads();
    int px = lane, s4 = w;
    unsigned short v[16];
#pragma unroll
    for (int j = 0; j < 16; j++) v[j] = tile[s4 * 16 + j][px];
    unsigned short* dst = xT + (size_t)b * 4194304 + (size_t)(ct * 4 + s4) * 262144 +
                          (size_t)(n0 + px) * 16;
    *(uint4*)&dst[0] = *(const uint4*)&v[0];
    *(uint4*)&dst[8] = *(const uint4*)&v[8];
    int gs0 = ct * 8 + s4 * 2;
    *(uint4*)&Xs[((size_t)px * 32 + (gs0 ^ (px & 31))) * 8] = *(const uint4*)&v[0];
    *(uint4*)&Xs[((size_t)px * 32 + ((gs0 + 1) ^ (px & 31))) * 8] = *(const uint4*)&v[8];
    __syncthreads();
  }

  f32x16 acc[2][2];
#pragma unroll
  for (int i = 0; i < 2; i++)
#pragma unroll
    for (int j = 0; j < 2; j++)
#pragma unroll
      for (int r = 0; r < 16; r++) acc[i][j][r] = 0.f;

#pragma unroll
  for (int ks = 0; ks < 16; ks++) {
    f16x8 bfr[2];
#pragma unroll
    for (int nt = 0; nt < 2; nt++) {
      int px = nt * 32 + l31;
      int gl = (ks * 2 + hi) ^ (px & 31);
      bfr[nt] = *(const f16x8*)&Xs[(px * 32 + gl) * 8];
    }
#pragma unroll
    for (int mj = 0; mj < 2; mj++) {
      int mt = w * 2 + mj;
      f16x8 afr = *(const f16x8*)(Wqvn + (size_t)(((mt * 16 + ks) * 2 + hi) * 32 + l31) * 8);
      acc[mj][0] = mfma32(afr, bfr[0], acc[mj][0]);
      acc[mj][1] = mfma32(afr, bfr[1], acc[mj][1]);
    }
  }

#pragma unroll
  for (int mj = 0; mj < 2; mj++) {
    int mt = w * 2 + mj;
#pragma unroll
    for (int nt = 0; nt < 2; nt++) {
      int px = nt * 32 + l31;
#pragma unroll
      for (int r = 0; r < 16; r++) {
        int og = mt * 32 + (r & 3) + 8 * (r >> 2) + 4 * hi;
        Ls[px * 264 + og] = f2h(acc[mj][nt][r] + bq[og]);
      }
    }
  }
  __syncthreads();
#pragma unroll
  for (int i = 0; i < 8; i++) {
    int item = i * 256 + tid;
    int og = item & 255, seg = item >> 8;
    int h = og >> 6, o = og & 63;
    unsigned short v[8];
#pragma unroll
    for (int j = 0; j < 8; j++) v[j] = Ls[(seg * 8 + j) * 264 + og];
    size_t hb = (size_t)(h * 8 + b);
    size_t nb16 = (size_t)(n0 >> 4) + (seg >> 1);
    *(uint4*)&qf[((hb * 1024 + nb16) * 2 + (seg & 1)) * 512 + o * 8] = *(const uint4*)v;
  }
}

// ---------------- dilated 3x3 conv + fused partial scores ---------------------
// R21: weights direct global->reg (L2-hot); only halo uses LDS (18 ds_reads per
// 72 MFMAs). Counted vmcnt(7) halo pipeline unchanged.
__global__ __launch_bounds__(256, 2) void convk(const unsigned short* __restrict__ xT,
                                                const unsigned short* __restrict__ Wkb,
                                                const float* __restrict__ bk,
                                                const unsigned short* __restrict__ zp,
                                                const unsigned short* __restrict__ qf,
                                                float* __restrict__ part) {
  __shared__ __align__(16) unsigned short LDSB[33280];  // 66560 B (halo 57344 / Ks 66560)
  int orig = (blockIdx.x & 7) * 128 + (blockIdx.x >> 3);
  int g = orig & 31, b = (orig >> 5) & 7, h = orig >> 8;
  int d = 1 << h;
  int gpd = 32 >> h;
  int s = g / gpd;
  int q0 = (g - s * gpd) * 4;
  int nq = 128 >> h;
  int tid = threadIdx.x, lane = tid & 63, w = tid >> 6;
  int l31 = lane & 31, hi = lane >> 5;
  const unsigned short* xb = xT + (size_t)b * 4194304;

  f32x16 acc[2][4];
#pragma unroll
  for (int i = 0; i < 2; i++)
#pragma unroll
    for (int j = 0; j < 4; j++)
#pragma unroll
      for (int r = 0; r < 16; r++) acc[i][j][r] = 0.f;

  const char* hptr[7];
  int hstr[7];
#pragma unroll
  for (int it = 0; it < 7; it++) {
    int p = it * 256 + tid;
    hptr[it] = (const char*)zp;
    hstr[it] = 0;
    if (p < 1728) {
      int px = p % 144;
      int sp = p / 144;
      int plane = sp % 6, slot = sp / 6;
      int q = q0 + plane - 1;
      int xc = px - d;
      bool ok = (q >= 0) & (q < nq) & (xc >= 0) & (xc < 128);
      if (ok) {
        hptr[it] = (const char*)(xb + (size_t)((s + q * d) * 128 + xc) * 16 + slot * 8);
        hstr[it] = 524288;
      }
    }
  }

  auto HSTAGE = [&](int bufi) {
    unsigned short* hb2 = LDSB + bufi * 14336;
#pragma unroll
    for (int it = 0; it < 7; it++) {
      int base = it * 256 + w * 64;
      __builtin_amdgcn_global_load_lds(
          (const __attribute__((address_space(1))) void*)hptr[it],
          (__attribute__((address_space(3))) void*)&hb2[(size_t)base * 8], 16, 0, 0);
      hptr[it] += hstr[it];
    }
  };

  // per-lane weight base for (h, hi, l31); tap stride 16384 elems, chunk stride 1024
  const unsigned short* wl = Wkb + ((size_t)(h * 9) * 32 + hi) * 512 + (size_t)l31 * 8;

  HSTAGE(0);
  HSTAGE(1);
#pragma unroll 1
  for (int c = 0; c < 16; c++) {
    if (c < 15) asm volatile("s_waitcnt vmcnt(7)" ::: "memory");
    else        asm volatile("s_waitcnt vmcnt(0)" ::: "memory");
    __builtin_amdgcn_s_barrier();
    __builtin_amdgcn_sched_barrier(0);
    const unsigned short* hb2 = LDSB + (c & 1) * 14336;
    const unsigned short* wc = wl + (size_t)c * 1024;
    __builtin_amdgcn_s_setprio(1);
#pragma unroll
    for (int tx = 0; tx < 3; tx++) {
      f16x8 bfr[6];
#pragma unroll
      for (int p6 = 0; p6 < 6; p6++)
        bfr[p6] = *(const f16x8*)&hb2[((hi * 6 + p6) * 144 + w * 32 + d * tx + l31) * 8];
#pragma unroll
      for (int ty = 0; ty < 3; ty++) {
        int t = ty * 3 + tx;
        f16x8 a0 = *(const f16x8*)(wc + (size_t)t * 16384);
        f16x8 a1 = *(const f16x8*)(wc + (size_t)t * 16384 + 256);
#pragma unroll
        for (int r = 0; r < 4; r++) {
          acc[0][r] = mfma32(a0, bfr[r + ty], acc[0][r]);
          acc[1][r] = mfma32(a1, bfr[r + ty], acc[1][r]);
        }
      }
    }
    __builtin_amdgcn_s_setprio(0);
    asm volatile("s_waitcnt lgkmcnt(0)" ::: "memory");
    __builtin_amdgcn_sched_barrier(0);
    __builtin_amdgcn_s_barrier();
    __builtin_amdgcn_sched_barrier(0);
    if (c < 14) HSTAGE(c & 1);
    __builtin_amdgcn_sched_barrier(0);
  }

  // ---- fused partial scores epilogue ----
  __syncthreads();
  unsigned short* Ks = LDSB;  // [64 p][520]
#pragma unroll
  for (int mo = 0; mo < 2; mo++)
#pragma unroll
    for (int r = 0; r < 4; r++)
#pragma unroll
      for (int reg = 0; reg < 16; reg++) {
        int p = mo * 32 + (reg & 3) + 8 * (reg >> 2) + 4 * hi;
        int nl = r * 128 + w * 32 + l31;
        Ks[p * 520 + nl] = f2h(acc[mo][r][reg] + bk[h * 64 + p]);
      }
  __syncthreads();
  int o0 = (w & 1) * 32, p0 = (w >> 1) * 32;
  f32x16 sacc;
#pragma unroll
  for (int r = 0; r < 16; r++) sacc[r] = 0.f;
  const unsigned short* qfb = qf + (size_t)(h * 8 + b) * 1048576;
#pragma unroll
  for (int ks = 0; ks < 32; ks++) {
    int r = ks >> 3;
    int x0 = (ks & 7) * 16;
    int y = s + (q0 + r) * d;
    size_t nb16 = (size_t)(y * 8) + (x0 >> 4);
    f16x8 aq = *(const f16x8*)(qfb + (nb16 * 2 + hi) * 512 + (o0 + l31) * 8);
    f16x8 bk2 = *(const f16x8*)&Ks[(p0 + l31) * 520 + ks * 16 + hi * 8];
    sacc = mfma32(aq, bk2, sacc);
  }
  float* pb = part + (size_t)((g * 4 + h) * 8 + b) * 4096;
#pragma unroll
  for (int reg = 0; reg < 16; reg++) {
    int o = o0 + (reg & 3) + 8 * (reg >> 2) + 4 * hi;
    pb[o * 64 + p0 + l31] = sacc[reg];
  }
}

// ---------------- softmax over p + obias = attn . bv ----------------
__global__ __launch_bounds__(256) void smax(const float* __restrict__ part,
                                            const float* __restrict__ bv,
                                            unsigned short* __restrict__ attn,
                                            float* __restrict__ obias) {
  int row = blockIdx.x * 4 + (threadIdx.x >> 6);
  int lane = threadIdx.x & 63;
  int h = row >> 9, b = (row >> 6) & 7, o = row & 63;
  float s = 0.f;
#pragma unroll
  for (int nch = 0; nch < 32; nch++)
    s += part[(size_t)((nch * 4 + h) * 8 + b) * 4096 + o * 64 + lane];
  s *= 0.0625f;  // 1/sqrt(256)
  float m = s;
#pragma unroll
  for (int k = 32; k > 0; k >>= 1) m = fmaxf(m, __shfl_xor(m, k, 64));
  float e = __expf(s - m);
  float sum = e;
#pragma unroll
  for (int k = 32; k > 0; k >>= 1) sum += __shfl_xor(sum, k, 64);
  float a = e / sum;
  attn[(size_t)(h * 8 + b) * 4096 + o * 64 + lane] = f2h(a);
  float ob = a * bv[h * 64 + lane];
#pragma unroll
  for (int k = 32; k > 0; k >>= 1) ob += __shfl_xor(ob, k, 64);
  if (lane == 0) obias[b * 256 + h * 64 + o] = ob;
}

// ---------------- avP: A2[b][oc][c] = attn @ Wv (f16, MFMA) -------------------
__global__ __launch_bounds__(256) void avP(const unsigned short* __restrict__ attn,
                                           const unsigned short* __restrict__ WvT,
                                           unsigned short* __restrict__ A2) {
  int b = blockIdx.x, h = blockIdx.y;
  int tid = threadIdx.x, lane = tid & 63, wq = tid >> 6;
  int l31 = lane & 31, hi = lane >> 5;
  const unsigned short* at = attn + (size_t)(h * 8 + b) * 4096;
  const unsigned short* wv = WvT + (size_t)h * 16384;
  f32x16 acc[2][2];
#pragma unroll
  for (int i = 0; i < 2; i++)
#pragma unroll
    for (int j = 0; j < 2; j++)
#pragma unroll
      for (int r = 0; r < 16; r++) acc[i][j][r] = 0.f;
#pragma unroll
  for (int ks = 0; ks < 4; ks++) {
    f16x8 a0 = *(const f16x8*)(at + (size_t)(l31)*64 + ks * 16 + hi * 8);
    f16x8 a1 = *(const f16x8*)(at + (size_t)(32 + l31) * 64 + ks * 16 + hi * 8);
    f16x8 b0 = *(const f16x8*)(wv + (size_t)(wq * 64 + l31) * 64 + ks * 16 + hi * 8);
    f16x8 b1 = *(const f16x8*)(wv + (size_t)(wq * 64 + 32 + l31) * 64 + ks * 16 + hi * 8);
    acc[0][0] = mfma32(a0, b0, acc[0][0]);
    acc[0][1] = mfma32(a0, b1, acc[0][1]);
    acc[1][0] = mfma32(a1, b0, acc[1][0]);
    acc[1][1] = mfma32(a1, b1, acc[1][1]);
  }
  unsigned short* a2b = A2 + (size_t)b * 65536;
#pragma unroll
  for (int mo = 0; mo < 2; mo++)
#pragma unroll
    for (int nf = 0; nf < 2; nf++)
#pragma unroll
      for (int r = 0; r < 16; r++) {
        int o = mo * 32 + (r & 3) + 8 * (r >> 2) + 4 * hi;
        int c = wq * 64 + nf * 32 + l31;
        a2b[(size_t)(h * 64 + o) * 256 + c] = f2h(acc[mo][nf][r]);
      }
}

// ---------------- outk2: out = A2 @ x + obias (R19 direct form) ---------------
__global__ __launch_bounds__(256) void outk2(const unsigned short* __restrict__ A2,
                                             const unsigned short* __restrict__ xT,
                                             const float* __restrict__ obias,
                                             float* __restrict__ out) {
  int n0 = blockIdx.x * 64, b = blockIdx.y;
  int tid = threadIdx.x, lane = tid & 63, w = tid >> 6;
  int l31 = lane & 31, hi = lane >> 5;
  const unsigned short* xb = xT + (size_t)b * 4194304;
  const unsigned short* a2b = A2 + (size_t)b * 65536;
  f32x16 acc[2][2];
#pragma unroll
  for (int i = 0; i < 2; i++)
#pragma unroll
    for (int j = 0; j < 2; j++)
#pragma unroll
      for (int r = 0; r < 16; r++) acc[i][j][r] = 0.f;
#pragma unroll
  for (int slab = 0; slab < 16; slab++) {
    f16x8 a0 = *(const f16x8*)(a2b + (size_t)(w * 64 + l31) * 256 + slab * 16 + hi * 8);
    f16x8 a1 = *(const f16x8*)(a2b + (size_t)(w * 64 + 32 + l31) * 256 + slab * 16 + hi * 8);
    f16x8 b0 = *(const f16x8*)(xb + (size_t)slab * 262144 + (size_t)(n0 + l31) * 16 + hi * 8);
    f16x8 b1 = *(const f16x8*)(xb + (size_t)slab * 262144 + (size_t)(n0 + 32 + l31) * 16 + hi * 8);
    acc[0][0] = mfma32(a0, b0, acc[0][0]);
    acc[0][1] = mfma32(a0, b1, acc[0][1]);
    acc[1][0] = mfma32(a1, b0, acc[1][0]);
    acc[1][1] = mfma32(a1, b1, acc[1][1]);
  }
  float* ob = out + (size_t)b * 4194304;
#pragma unroll
  for (int mo = 0; mo < 2; mo++)
#pragma unroll
    for (int nf = 0; nf < 2; nf++)
#pragma unroll
      for (int r = 0; r < 16; r++) {
        int oc = w * 64 + mo * 32 + (r & 3) + 8 * (r >> 2) + 4 * hi;
        int n = n0 + nf * 32 + l31;
        ob[(size_t)oc * 16384 + n] = acc[mo][nf][r] + obias[b * 256 + oc];
      }
}

extern "C" void kernel_launch(void* const* d_in, const int* in_sizes, int n_in,
                              void* d_out, int out_size, void* d_ws, size_t ws_size,
                              hipStream_t stream) {
  const float* x  = (const float*)d_in[0];
  const float* Wq = (const float*)d_in[1];
  const float* bq = (const float*)d_in[2];
  const float* Wk = (const float*)d_in[3];
  const float* bk = (const float*)d_in[4];
  const float* Wv = (const float*)d_in[5];
  const float* bv = (const float*)d_in[6];
  float* out = (float*)d_out;

  char* ws = (char*)d_ws;
  unsigned short* A2   = (unsigned short*)(ws);
  float*          obias = (float*)(ws + 1048576);
  unsigned short* xT   = (unsigned short*)(ws + 67108864);
  unsigned short* attn = (unsigned short*)(ws + 134217728);
  unsigned short* Wqvn = (unsigned short*)(ws + 134479872);
  unsigned short* WvT  = (unsigned short*)(ws + 134610944);
  unsigned short* Wkb  = (unsigned short*)(ws + 134742016);
  unsigned short* zp   = (unsigned short*)(ws + 135921664);
  unsigned short* qf = (unsigned short*)d_out + 33554432;
  float* part = (float*)d_out;

  prep<<<dim3(2816), dim3(256), 0, stream>>>(Wq, Wv, Wk, Wqvn, Wkb, zp);
  xproj<<<dim3(256, 8), dim3(256), 0, stream>>>(x, Wqvn, bq, xT, qf);
  convk<<<dim3(1024), dim3(256), 0, stream>>>(xT, Wkb, bk, zp, qf, part);
  smax<<<dim3(512), dim3(256), 0, stream>>>(part, bv, attn, obias);
  avP<<<dim3(8, 4), dim3(256), 0, stream>>>(attn, WvT, A2);
  outk2<<<dim3(256, 8), dim3(256), 0, stream>>>(A2, xT, obias, out);
}

// Round 22
// 277.159 us; speedup vs baseline: 1.0644x; 1.0644x over previous
//
#include <hip/hip_runtime.h>
#include <hip/hip_bf16.h>

// Channel attention (4 heads, dilated 3x3 key convs d=1,2,4,8), f16 MFMA pipeline.
// R22: revert to R19 (best measured, 277.6us). convk: halo+weights both LDS-staged
// (counted vmcnt(7)); R21's global weight loads confirmed the latency-class
// failure (202us, 32%). outk2 direct form. convk is at its structural LDS-BW
// ceiling (reads/MFMA = 0.5 minimal under the 128-AGPR budget -> ~53% MfmaUtil).
//
// ws layout (bytes):
//   A2   : [0, 1Mi)            f16 A2 = attn@Wv ; obias fp32 [1048576,1056768)
//   xT2  : [67108864,134217728) f16 [b][slab16][n][16]
//   attn : [134217728,134479872) f16 [h][b][o][p]
//   Wqvn : [134479872,134610944) f16 q A-frag-native [mt8][ks16][hi2][m32][8]
//   WvT  : [134610944,134742016) f16 [h][c256][p64]
//   Wkb  : [134742016,135921664) f16 [h][t][ks32][p64][8]
//   zpage: [135921664,135922176) zeros
// d_out scratch: part fp32 [0,16Mi); qf f16 [64Mi,128Mi)
//   qf[((hb*1024 + nb16)*2 + hi)*512 + o*8 + j] = q[h,b][o][nb16*16+hi*8+j]

typedef __attribute__((ext_vector_type(8))) _Float16 f16x8;
typedef __attribute__((ext_vector_type(4))) float f32x4;
typedef __attribute__((ext_vector_type(16))) float f32x16;

__device__ __forceinline__ unsigned short f2h(float f) {
  union { _Float16 h; unsigned short u; } v;
  v.h = (_Float16)f;
  return v.u;
}

__device__ __forceinline__ f32x16 mfma32(f16x8 a, f16x8 b, f32x16 c) {
  return __builtin_amdgcn_mfma_f32_32x32x16_f16(a, b, c, 0, 0, 0);
}

// ---------------- weight prep ----------------
__global__ __launch_bounds__(256) void prep(const float* __restrict__ Wq,
                                            const float* __restrict__ Wv,
                                            const float* __restrict__ Wk,
                                            unsigned short* __restrict__ Wqvn,
                                            unsigned short* __restrict__ Wkb,
                                            unsigned short* __restrict__ zp) {
  int i = blockIdx.x * 256 + threadIdx.x;
  if (blockIdx.x == 0) zp[threadIdx.x] = 0;  // 512 B zero page
  const int total = 131072 + 589824;
  if (i >= total) return;
  if (i < 65536) {
    int jj = i & 7;
    int m31 = (i >> 3) & 31;
    int hi = (i >> 8) & 1;
    int ks = (i >> 9) & 15;
    int mt = i >> 13;
    int row = mt * 32 + m31;
    int ch = ks * 16 + hi * 8 + jj;
    Wqvn[i] = f2h(Wq[row * 256 + ch]);
  } else if (i < 131072) {
    int j2 = i - 65536;
    int p = j2 & 63;
    int c = (j2 >> 6) & 255;
    int h = j2 >> 14;
    Wqvn[i] = f2h(Wv[(size_t)(h * 64 + p) * 256 + c]);
  } else {
    int j = i - 131072;  // (((h*9+t)*32 + ks)*64 + p)*8 + jj
    int jj = j & 7;
    int p = (j >> 3) & 63;
    int ks = (j >> 9) & 31;
    int ht = j >> 14;
    int t = ht % 9;
    int h = ht / 9;
    Wkb[j] = f2h(Wk[(size_t)((h * 64 + p) * 256 + ks * 8 + jj) * 9 + t]);
  }
}

// ---------------- fused xpose + q-projection ----------------------------------
__global__ __launch_bounds__(256) void xproj(const float* __restrict__ x,
                                             const unsigned short* __restrict__ Wqvn,
                                             const float* __restrict__ bq,
                                             unsigned short* __restrict__ xT,
                                             unsigned short* __restrict__ qf) {
  __shared__ unsigned short tile[64][66];                 // 8448 B
  __shared__ __align__(16) unsigned short Xs[2048 * 8];   // 32 KB
  __shared__ __align__(16) unsigned short Ls[64 * 264];   // 33.8 KB
  int n0 = blockIdx.x * 64, b = blockIdx.y;
  int tid = threadIdx.x, lane = tid & 63, w = tid >> 6;
  int l31 = lane & 31, hi = lane >> 5;

#pragma unroll 1
  for (int ct = 0; ct < 4; ct++) {
    int c0 = ct * 64;
    int r = tid >> 2, q = tid & 3;
    const float* src = x + (size_t)b * 4194304 + (size_t)(c0 + r) * 16384 + n0 + q * 16;
#pragma unroll
    for (int i = 0; i < 4; i++) {
      float4 v = *(const float4*)(src + i * 4);
      tile[r][q * 16 + i * 4 + 0] = f2h(v.x);
      tile[r][q * 16 + i * 4 + 1] = f2h(v.y);
      tile[r][q * 16 + i * 4 + 2] = f2h(v.z);
      tile[r][q * 16 + i * 4 + 3] = f2h(v.w);
    }
    __syncthreads();
    int px = lane, s4 = w;
    unsigned short v[16];
#pragma unroll
    for (int j = 0; j < 16; j++) v[j] = tile[s4 * 16 + j][px];
    unsigned short* dst = xT + (size_t)b * 4194304 + (size_t)(ct * 4 + s4) * 262144 +
                          (size_t)(n0 + px) * 16;
    *(uint4*)&dst[0] = *(const uint4*)&v[0];
    *(uint4*)&dst[8] = *(const uint4*)&v[8];
    int gs0 = ct * 8 + s4 * 2;
    *(uint4*)&Xs[((size_t)px * 32 + (gs0 ^ (px & 31))) * 8] = *(const uint4*)&v[0];
    *(uint4*)&Xs[((size_t)px * 32 + ((gs0 + 1) ^ (px & 31))) * 8] = *(const uint4*)&v[8];
    __syncthreads();
  }

  // ---- phase 2: q-GEMM from Xs
  f32x16 acc[2][2];
#pragma unroll
  for (int i = 0; i < 2; i++)
#pragma unroll
    for (int j = 0; j < 2; j++)
#pragma unroll
      for (int r = 0; r < 16; r++) acc[i][j][r] = 0.f;

#pragma unroll
  for (int ks = 0; ks < 16; ks++) {
    f16x8 bfr[2];
#pragma unroll
    for (int nt = 0; nt < 2; nt++) {
      int px = nt * 32 + l31;
      int gl = (ks * 2 + hi) ^ (px & 31);
      bfr[nt] = *(const f16x8*)&Xs[(px * 32 + gl) * 8];
    }
#pragma unroll
    for (int mj = 0; mj < 2; mj++) {
      int mt = w * 2 + mj;
      f16x8 afr = *(const f16x8*)(Wqvn + (size_t)(((mt * 16 + ks) * 2 + hi) * 32 + l31) * 8);
      acc[mj][0] = mfma32(afr, bfr[0], acc[mj][0]);
      acc[mj][1] = mfma32(afr, bfr[1], acc[mj][1]);
    }
  }

  // write q+bias into Ls[px][og]
#pragma unroll
  for (int mj = 0; mj < 2; mj++) {
    int mt = w * 2 + mj;
#pragma unroll
    for (int nt = 0; nt < 2; nt++) {
      int px = nt * 32 + l31;
#pragma unroll
      for (int r = 0; r < 16; r++) {
        int og = mt * 32 + (r & 3) + 8 * (r >> 2) + 4 * hi;
        Ls[px * 264 + og] = f2h(acc[mj][nt][r] + bq[og]);
      }
    }
  }
  __syncthreads();
#pragma unroll
  for (int i = 0; i < 8; i++) {
    int item = i * 256 + tid;
    int og = item & 255, seg = item >> 8;
    int h = og >> 6, o = og & 63;
    unsigned short v[8];
#pragma unroll
    for (int j = 0; j < 8; j++) v[j] = Ls[(seg * 8 + j) * 264 + og];
    size_t hb = (size_t)(h * 8 + b);
    size_t nb16 = (size_t)(n0 >> 4) + (seg >> 1);
    *(uint4*)&qf[((hb * 1024 + nb16) * 2 + (seg & 1)) * 512 + o * 8] = *(const uint4*)v;
  }
}

// ---------------- dilated 3x3 conv + fused partial scores (R19 form) ----------
__global__ __launch_bounds__(256, 2) void convk(const unsigned short* __restrict__ xT,
                                                const unsigned short* __restrict__ Wkb,
                                                const float* __restrict__ bk,
                                                const unsigned short* __restrict__ zp,
                                                const unsigned short* __restrict__ qf,
                                                float* __restrict__ part) {
  __shared__ __align__(16) unsigned short LDSB[38912];  // 77824 B
  unsigned short* Wsb = LDSB + 28672;
  int orig = (blockIdx.x & 7) * 128 + (blockIdx.x >> 3);
  int g = orig & 31, b = (orig >> 5) & 7, h = orig >> 8;
  int d = 1 << h;
  int gpd = 32 >> h;
  int s = g / gpd;
  int q0 = (g - s * gpd) * 4;
  int nq = 128 >> h;
  int tid = threadIdx.x, lane = tid & 63, w = tid >> 6;
  int l31 = lane & 31, hi = lane >> 5;
  const unsigned short* xb = xT + (size_t)b * 4194304;

  f32x16 acc[2][4];
#pragma unroll
  for (int i = 0; i < 2; i++)
#pragma unroll
    for (int j = 0; j < 4; j++)
#pragma unroll
      for (int r = 0; r < 16; r++) acc[i][j][r] = 0.f;

  const char* hptr[7];
  int hstr[7];
#pragma unroll
  for (int it = 0; it < 7; it++) {
    int p = it * 256 + tid;
    hptr[it] = (const char*)zp;
    hstr[it] = 0;
    if (p < 1728) {
      int px = p % 144;
      int sp = p / 144;
      int plane = sp % 6, slot = sp / 6;
      int q = q0 + plane - 1;
      int xc = px - d;
      bool ok = (q >= 0) & (q < nq) & (xc >= 0) & (xc < 128);
      if (ok) {
        hptr[it] = (const char*)(xb + (size_t)((s + q * d) * 128 + xc) * 16 + slot * 8);
        hstr[it] = 524288;
      }
    }
  }
  const char* wptr[5];
  int wstr[5];
#pragma unroll
  for (int it = 0; it < 5; it++) {
    int p = it * 256 + tid;
    wptr[it] = (const char*)zp;
    wstr[it] = 0;
    if (p < 1152) {
      int pp = p & 63, ts = p >> 6;
      int t = ts >> 1, slot = ts & 1;
      wptr[it] = (const char*)(Wkb + (size_t)(((h * 9 + t) * 32 + slot) * 64 + pp) * 8);
      wstr[it] = 2048;
    }
  }

  auto HSTAGE = [&](int bufi) {
    unsigned short* hb2 = LDSB + bufi * 14336;
#pragma unroll
    for (int it = 0; it < 7; it++) {
      int base = it * 256 + w * 64;
      __builtin_amdgcn_global_load_lds(
          (const __attribute__((address_space(1))) void*)hptr[it],
          (__attribute__((address_space(3))) void*)&hb2[(size_t)base * 8], 16, 0, 0);
      hptr[it] += hstr[it];
    }
  };
  auto WSTAGE = [&]() {
#pragma unroll
    for (int it = 0; it < 5; it++) {
      int base = it * 256 + w * 64;
      __builtin_amdgcn_global_load_lds(
          (const __attribute__((address_space(1))) void*)wptr[it],
          (__attribute__((address_space(3))) void*)&Wsb[(size_t)base * 8], 16, 0, 0);
      wptr[it] += wstr[it];
    }
  };

  HSTAGE(0);
  WSTAGE();
  HSTAGE(1);
#pragma unroll 1
  for (int c = 0; c < 16; c++) {
    if (c < 15) asm volatile("s_waitcnt vmcnt(7)" ::: "memory");
    else        asm volatile("s_waitcnt vmcnt(0)" ::: "memory");
    __builtin_amdgcn_s_barrier();
    __builtin_amdgcn_sched_barrier(0);
    const unsigned short* hb2 = LDSB + (c & 1) * 14336;
    __builtin_amdgcn_s_setprio(1);
#pragma unroll
    for (int tx = 0; tx < 3; tx++) {
      f16x8 bfr[6];
#pragma unroll
      for (int p6 = 0; p6 < 6; p6++)
        bfr[p6] = *(const f16x8*)&hb2[((hi * 6 + p6) * 144 + w * 32 + d * tx + l31) * 8];
#pragma unroll
      for (int ty = 0; ty < 3; ty++) {
        int t = ty * 3 + tx;
        f16x8 a0 = *(const f16x8*)&Wsb[((t * 2 + hi) * 64 + l31) * 8];
        f16x8 a1 = *(const f16x8*)&Wsb[((t * 2 + hi) * 64 + 32 + l31) * 8];
#pragma unroll
        for (int r = 0; r < 4; r++) {
          acc[0][r] = mfma32(a0, bfr[r + ty], acc[0][r]);
          acc[1][r] = mfma32(a1, bfr[r + ty], acc[1][r]);
        }
      }
    }
    __builtin_amdgcn_s_setprio(0);
    asm volatile("s_waitcnt lgkmcnt(0)" ::: "memory");
    __builtin_amdgcn_sched_barrier(0);
    __builtin_amdgcn_s_barrier();
    __builtin_amdgcn_sched_barrier(0);
    if (c < 15) WSTAGE();
    if (c < 14) HSTAGE(c & 1);
    __builtin_amdgcn_sched_barrier(0);
  }

  // ---- fused partial scores epilogue ----
  __syncthreads();
  unsigned short* Ks = LDSB;  // [64 p][520]
#pragma unroll
  for (int mo = 0; mo < 2; mo++)
#pragma unroll
    for (int r = 0; r < 4; r++)
#pragma unroll
      for (int reg = 0; reg < 16; reg++) {
        int p = mo * 32 + (reg & 3) + 8 * (reg >> 2) + 4 * hi;
        int nl = r * 128 + w * 32 + l31;
        Ks[p * 520 + nl] = f2h(acc[mo][r][reg] + bk[h * 64 + p]);
      }
  __syncthreads();
  int o0 = (w & 1) * 32, p0 = (w >> 1) * 32;
  f32x16 sacc;
#pragma unroll
  for (int r = 0; r < 16; r++) sacc[r] = 0.f;
  const unsigned short* qfb = qf + (size_t)(h * 8 + b) * 1048576;
#pragma unroll
  for (int ks = 0; ks < 32; ks++) {
    int r = ks >> 3;
    int x0 = (ks & 7) * 16;
    int y = s + (q0 + r) * d;
    size_t nb16 = (size_t)(y * 8) + (x0 >> 4);
    f16x8 aq = *(const f16x8*)(qfb + (nb16 * 2 + hi) * 512 + (o0 + l31) * 8);
    f16x8 bk2 = *(const f16x8*)&Ks[(p0 + l31) * 520 + ks * 16 + hi * 8];
    sacc = mfma32(aq, bk2, sacc);
  }
  float* pb = part + (size_t)((g * 4 + h) * 8 + b) * 4096;
#pragma unroll
  for (int reg = 0; reg < 16; reg++) {
    int o = o0 + (reg & 3) + 8 * (reg >> 2) + 4 * hi;
    pb[o * 64 + p0 + l31] = sacc[reg];
  }
}

// ---------------- softmax over p + obias = attn . bv ----------------
__global__ __launch_bounds__(256) void smax(const float* __restrict__ part,
                                            const float* __restrict__ bv,
                                            unsigned short* __restrict__ attn,
                                            float* __restrict__ obias) {
  int row = blockIdx.x * 4 + (threadIdx.x >> 6);
  int lane = threadIdx.x & 63;
  int h = row >> 9, b = (row >> 6) & 7, o = row & 63;
  float s = 0.f;
#pragma unroll
  for (int nch = 0; nch < 32; nch++)
    s += part[(size_t)((nch * 4 + h) * 8 + b) * 4096 + o * 64 + lane];
  s *= 0.0625f;  // 1/sqrt(256)
  float m = s;
#pragma unroll
  for (int k = 32; k > 0; k >>= 1) m = fmaxf(m, __shfl_xor(m, k, 64));
  float e = __expf(s - m);
  float sum = e;
#pragma unroll
  for (int k = 32; k > 0; k >>= 1) sum += __shfl_xor(sum, k, 64);
  float a = e / sum;
  attn[(size_t)(h * 8 + b) * 4096 + o * 64 + lane] = f2h(a);
  float ob = a * bv[h * 64 + lane];
#pragma unroll
  for (int k = 32; k > 0; k >>= 1) ob += __shfl_xor(ob, k, 64);
  if (lane == 0) obias[b * 256 + h * 64 + o] = ob;
}

// ---------------- avP: A2[b][oc][c] = attn @ Wv (f16, MFMA) -------------------
__global__ __launch_bounds__(256) void avP(const unsigned short* __restrict__ attn,
                                           const unsigned short* __restrict__ WvT,
                                           unsigned short* __restrict__ A2) {
  int b = blockIdx.x, h = blockIdx.y;
  int tid = threadIdx.x, lane = tid & 63, wq = tid >> 6;
  int l31 = lane & 31, hi = lane >> 5;
  const unsigned short* at = attn + (size_t)(h * 8 + b) * 4096;
  const unsigned short* wv = WvT + (size_t)h * 16384;
  f32x16 acc[2][2];
#pragma unroll
  for (int i = 0; i < 2; i++)
#pragma unroll
    for (int j = 0; j < 2; j++)
#pragma unroll
      for (int r = 0; r < 16; r++) acc[i][j][r] = 0.f;
#pragma unroll
  for (int ks = 0; ks < 4; ks++) {
    f16x8 a0 = *(const f16x8*)(at + (size_t)(l31)*64 + ks * 16 + hi * 8);
    f16x8 a1 = *(const f16x8*)(at + (size_t)(32 + l31) * 64 + ks * 16 + hi * 8);
    f16x8 b0 = *(const f16x8*)(wv + (size_t)(wq * 64 + l31) * 64 + ks * 16 + hi * 8);
    f16x8 b1 = *(const f16x8*)(wv + (size_t)(wq * 64 + 32 + l31) * 64 + ks * 16 + hi * 8);
    acc[0][0] = mfma32(a0, b0, acc[0][0]);
    acc[0][1] = mfma32(a0, b1, acc[0][1]);
    acc[1][0] = mfma32(a1, b0, acc[1][0]);
    acc[1][1] = mfma32(a1, b1, acc[1][1]);
  }
  unsigned short* a2b = A2 + (size_t)b * 65536;
#pragma unroll
  for (int mo = 0; mo < 2; mo++)
#pragma unroll
    for (int nf = 0; nf < 2; nf++)
#pragma unroll
      for (int r = 0; r < 16; r++) {
        int o = mo * 32 + (r & 3) + 8 * (r >> 2) + 4 * hi;
        int c = wq * 64 + nf * 32 + l31;
        a2b[(size_t)(h * 64 + o) * 256 + c] = f2h(acc[mo][nf][r]);
      }
}

// ---------------- outk2: out = A2 @ x + obias (direct coalesced reads) --------
__global__ __launch_bounds__(256) void outk2(const unsigned short* __restrict__ A2,
                                             const unsigned short* __restrict__ xT,
                                             const float* __restrict__ obias,
                                             float* __restrict__ out) {
  int n0 = blockIdx.x * 64, b = blockIdx.y;
  int tid = threadIdx.x, lane = tid & 63, w = tid >> 6;
  int l31 = lane & 31, hi = lane >> 5;
  const unsigned short* xb = xT + (size_t)b * 4194304;
  const unsigned short* a2b = A2 + (size_t)b * 65536;
  f32x16 acc[2][2];
#pragma unroll
  for (int i = 0; i < 2; i++)
#pragma unroll
    for (int j = 0; j < 2; j++)
#pragma unroll
      for (int r = 0; r < 16; r++) acc[i][j][r] = 0.f;
#pragma unroll
  for (int slab = 0; slab < 16; slab++) {
    f16x8 a0 = *(const f16x8*)(a2b + (size_t)(w * 64 + l31) * 256 + slab * 16 + hi * 8);
    f16x8 a1 = *(const f16x8*)(a2b + (size_t)(w * 64 + 32 + l31) * 256 + slab * 16 + hi * 8);
    f16x8 b0 = *(const f16x8*)(xb + (size_t)slab * 262144 + (size_t)(n0 + l31) * 16 + hi * 8);
    f16x8 b1 = *(const f16x8*)(xb + (size_t)slab * 262144 + (size_t)(n0 + 32 + l31) * 16 + hi * 8);
    acc[0][0] = mfma32(a0, b0, acc[0][0]);
    acc[0][1] = mfma32(a0, b1, acc[0][1]);
    acc[1][0] = mfma32(a1, b0, acc[1][0]);
    acc[1][1] = mfma32(a1, b1, acc[1][1]);
  }
  float* ob = out + (size_t)b * 4194304;
#pragma unroll
  for (int mo = 0; mo < 2; mo++)
#pragma unroll
    for (int nf = 0; nf < 2; nf++)
#pragma unroll
      for (int r = 0; r < 16; r++) {
        int oc = w * 64 + mo * 32 + (r & 3) + 8 * (r >> 2) + 4 * hi;
        int n = n0 + nf * 32 + l31;
        ob[(size_t)oc * 16384 + n] = acc[mo][nf][r] + obias[b * 256 + oc];
      }
}

extern "C" void kernel_launch(void* const* d_in, const int* in_sizes, int n_in,
                              void* d_out, int out_size, void* d_ws, size_t ws_size,
                              hipStream_t stream) {
  const float* x  = (const float*)d_in[0];
  const float* Wq = (const float*)d_in[1];
  const float* bq = (const float*)d_in[2];
  const float* Wk = (const float*)d_in[3];
  const float* bk = (const float*)d_in[4];
  const float* Wv = (const float*)d_in[5];
  const float* bv = (const float*)d_in[6];
  float* out = (float*)d_out;

  char* ws = (char*)d_ws;
  unsigned short* A2   = (unsigned short*)(ws);
  float*          obias = (float*)(ws + 1048576);
  unsigned short* xT   = (unsigned short*)(ws + 67108864);
  unsigned short* attn = (unsigned short*)(ws + 134217728);
  unsigned short* Wqvn = (unsigned short*)(ws + 134479872);
  unsigned short* WvT  = (unsigned short*)(ws + 134610944);
  unsigned short* Wkb  = (unsigned short*)(ws + 134742016);
  unsigned short* zp   = (unsigned short*)(ws + 135921664);
  unsigned short* qf = (unsigned short*)d_out + 33554432;
  float* part = (float*)d_out;

  prep<<<dim3(2816), dim3(256), 0, stream>>>(Wq, Wv, Wk, Wqvn, Wkb, zp);
  xproj<<<dim3(256, 8), dim3(256), 0, stream>>>(x, Wqvn, bq, xT, qf);
  convk<<<dim3(1024), dim3(256), 0, stream>>>(xT, Wkb, bk, zp, qf, part);
  smax<<<dim3(512), dim3(256), 0, stream>>>(part, bv, attn, obias);
  avP<<<dim3(8, 4), dim3(256), 0, stream>>>(attn, WvT, A2);
  outk2<<<dim3(256, 8), dim3(256), 0, stream>>>(A2, xT, obias, out);
}